// Round 7
// baseline (275.497 us; speedup 1.0000x reference)
//
#include <hip/hip_runtime.h>

#define D 64

// ---- bf16 helpers (RNE), raw ushort storage ------------------------------
__device__ __forceinline__ unsigned short f2bf(float f) {
    unsigned u = __float_as_uint(f);
    unsigned r = (u + 0x7FFFu + ((u >> 16) & 1u)) >> 16;
    return (unsigned short)r;
}
__device__ __forceinline__ float bf2f(unsigned short h) {
    return __uint_as_float((unsigned)h << 16);
}

typedef __attribute__((ext_vector_type(8))) short bf16x8;
typedef __attribute__((ext_vector_type(4))) float f32x4;
typedef __attribute__((ext_vector_type(4))) unsigned uivec4;

// ============ prep: zero deg/dhist + convert x (fp32) -> Xb (bf16) ==========
__global__ void prep_kernel(const float* __restrict__ x, unsigned short* __restrict__ xb,
                            int total, int* __restrict__ deg, int N,
                            const float* __restrict__ Wself,
                            const float* __restrict__ Wmsg,
                            unsigned short* __restrict__ Bt, int n_layers,
                            int* __restrict__ dhist) {
    int i = blockIdx.x * blockDim.x + threadIdx.x;
    if (i < N) deg[i] = 0;
    if (i < 1024) dhist[i] = 0;
    // weight transpose + hi/lo split (tiny: n_layers*64*128 threads)
    int wtotal = n_layers * D * 2 * D;   // l * 8192
    if (i < wtotal) {
        int k = i & 127;
        int n = (i >> 7) & 63;
        int l = i >> 13;
        float w = (k < D) ? Wself[(size_t)l * D * D + k * D + n]
                          : Wmsg [(size_t)l * D * D + (k - D) * D + n];
        unsigned short hi = f2bf(w);
        unsigned short lo = f2bf(w - bf2f(hi));
        size_t base = (size_t)l * 2 * D * 2 * D;     // l * 16384
        Bt[base + (size_t)n * 128 + k] = hi;
        Bt[base + 8192 + (size_t)n * 128 + k] = lo;
    }
    int base = i * 4;
    if (base + 4 <= total) {
        float4 v = *reinterpret_cast<const float4*>(x + base);
        ushort4 o;
        o.x = f2bf(v.x); o.y = f2bf(v.y); o.z = f2bf(v.z); o.w = f2bf(v.w);
        *reinterpret_cast<ushort4*>(xb + base) = o;
    } else if (base < total) {
        for (int k = base; k < total; ++k) xb[k] = f2bf(x[k]);
    }
}

// ================= CSR build: hist captures per-edge rank ===================
__global__ void hist_rank_kernel(const int* __restrict__ dst, int* __restrict__ deg,
                                 int* __restrict__ rank, int E) {
    int i = blockIdx.x * blockDim.x + threadIdx.x;
    int base = i * 8;
    if (base + 8 <= E) {
        int4 d0 = *reinterpret_cast<const int4*>(dst + base);
        int4 d1 = *reinterpret_cast<const int4*>(dst + base + 4);
        int4 r0, r1;                       // 8 independent atomic chains
        r0.x = atomicAdd(&deg[d0.x], 1);
        r0.y = atomicAdd(&deg[d0.y], 1);
        r0.z = atomicAdd(&deg[d0.z], 1);
        r0.w = atomicAdd(&deg[d0.w], 1);
        r1.x = atomicAdd(&deg[d1.x], 1);
        r1.y = atomicAdd(&deg[d1.y], 1);
        r1.z = atomicAdd(&deg[d1.z], 1);
        r1.w = atomicAdd(&deg[d1.w], 1);
        *reinterpret_cast<int4*>(rank + base) = r0;
        *reinterpret_cast<int4*>(rank + base + 4) = r1;
    } else {
        for (int e = base; e < E; ++e) rank[e] = atomicAdd(&deg[dst[e]], 1);
    }
}

// scan_k1: block sums of deg + degree histogram (LDS-privatized)
__global__ void scan_k1(const int* __restrict__ deg, int* __restrict__ bsum, int n,
                        int* __restrict__ dhist) {
    __shared__ int sh[256];
    __shared__ int lh[1024];
    int t = threadIdx.x;
    for (int i = t; i < 1024; i += 256) lh[i] = 0;
    __syncthreads();
    int g = blockIdx.x * 256 + t;
    int v = (g < n) ? deg[g] : 0;
    if (g < n) atomicAdd(&lh[min(v, 1023)], 1);
    sh[t] = v;
    __syncthreads();
    for (int off = 1; off < 256; off <<= 1) {
        int u = (t >= off) ? sh[t - off] : 0;
        __syncthreads();
        sh[t] += u;
        __syncthreads();
    }
    if (t == 255) bsum[blockIdx.x] = sh[255];
    __syncthreads();
    for (int i = t; i < 1024; i += 256) {
        int c = lh[i];
        if (c) atomicAdd(&dhist[i], c);
    }
}

// scan_k2: scan block sums + suffix-scan of dhist (descending-degree bases)
__global__ void scan_k2(const int* __restrict__ bsum, int* __restrict__ boff, int nb,
                        const int* __restrict__ dhist, int* __restrict__ dbase) {
    __shared__ int sh[1024];
    int t = threadIdx.x;
    int v = (t < nb) ? bsum[t] : 0;
    sh[t] = v;
    __syncthreads();
    for (int off = 1; off < 1024; off <<= 1) {
        int u = (t >= off) ? sh[t - off] : 0;
        __syncthreads();
        sh[t] += u;
        __syncthreads();
    }
    if (t < nb) boff[t] = sh[t] - v;
    __syncthreads();
    int rb = 1023 - t;
    int dv = dhist[rb];
    sh[t] = dv;
    __syncthreads();
    for (int off = 1; off < 1024; off <<= 1) {
        int u = (t >= off) ? sh[t - off] : 0;
        __syncthreads();
        sh[t] += u;
        __syncthreads();
    }
    dbase[rb] = sh[t] - dv;
}

// scan_k3 + perm_nodes fused: same grid, both consume deg + precomputed bases.
// Writes row_ptr (exclusive scan) AND nperm (descending-degree counting sort).
__global__ void scan_k3_perm(const int* __restrict__ deg, const int* __restrict__ boff,
                             int* __restrict__ row_ptr, int n,
                             int* __restrict__ dbase, int* __restrict__ nperm) {
    __shared__ int sh[256];
    __shared__ int lh[1024];
    __shared__ int lbase[1024];
    int t = threadIdx.x;
    for (int i = t; i < 1024; i += 256) lh[i] = 0;
    int g = blockIdx.x * 256 + t;
    int v = (g < n) ? deg[g] : 0;
    sh[t] = v;
    __syncthreads();
    for (int off = 1; off < 256; off <<= 1) {
        int u = (t >= off) ? sh[t - off] : 0;
        __syncthreads();
        sh[t] += u;
        __syncthreads();
    }
    if (g < n) {
        int excl = sh[t] - v + boff[blockIdx.x];
        row_ptr[g] = excl;
        if (g == n - 1) row_ptr[n] = excl + v;
    }
    // counting-sort part (lh zeroing was synced by the scan's barriers)
    int b = 0, lrank = 0;
    if (g < n) {
        b = min(v, 1023);
        lrank = atomicAdd(&lh[b], 1);
    }
    __syncthreads();
    for (int i = t; i < 1024; i += 256) {
        int c = lh[i];
        lbase[i] = c ? atomicAdd(&dbase[i], c) : 0;
    }
    __syncthreads();
    if (g < n) nperm[lbase[b] + lrank] = g;
}

// atomic-free permutation: pos = row_ptr[dst] + rank
__global__ void perm_rank_kernel(const int* __restrict__ src, const int* __restrict__ dst,
                                 const int* __restrict__ rank, const int* __restrict__ row_ptr,
                                 int* __restrict__ sorted_src, int E) {
    int i = blockIdx.x * blockDim.x + threadIdx.x;
    int base = i * 8;
    if (base + 8 <= E) {
        int4 d0 = *reinterpret_cast<const int4*>(dst + base);
        int4 d1 = *reinterpret_cast<const int4*>(dst + base + 4);
        int4 s0 = *reinterpret_cast<const int4*>(src + base);
        int4 s1 = *reinterpret_cast<const int4*>(src + base + 4);
        int4 r0 = *reinterpret_cast<const int4*>(rank + base);
        int4 r1 = *reinterpret_cast<const int4*>(rank + base + 4);
        int p0 = row_ptr[d0.x] + r0.x;
        int p1 = row_ptr[d0.y] + r0.y;
        int p2 = row_ptr[d0.z] + r0.z;
        int p3 = row_ptr[d0.w] + r0.w;
        int p4 = row_ptr[d1.x] + r1.x;
        int p5 = row_ptr[d1.y] + r1.y;
        int p6 = row_ptr[d1.z] + r1.z;
        int p7 = row_ptr[d1.w] + r1.w;
        __builtin_nontemporal_store(s0.x, &sorted_src[p0]);
        __builtin_nontemporal_store(s0.y, &sorted_src[p1]);
        __builtin_nontemporal_store(s0.z, &sorted_src[p2]);
        __builtin_nontemporal_store(s0.w, &sorted_src[p3]);
        __builtin_nontemporal_store(s1.x, &sorted_src[p4]);
        __builtin_nontemporal_store(s1.y, &sorted_src[p5]);
        __builtin_nontemporal_store(s1.z, &sorted_src[p6]);
        __builtin_nontemporal_store(s1.w, &sorted_src[p7]);
    } else {
        for (int e = base; e < E; ++e)
            sorted_src[row_ptr[dst[e]] + rank[e]] = src[e];
    }
}

// ---- accumulate 16 bf16 feats (2 x uivec4) into fp32 lanes -----------------
__device__ __forceinline__ void acc16(float* ac, uivec4 u0, uivec4 u1) {
    ac[0]  += __uint_as_float(u0[0] << 16);
    ac[1]  += __uint_as_float(u0[0] & 0xFFFF0000u);
    ac[2]  += __uint_as_float(u0[1] << 16);
    ac[3]  += __uint_as_float(u0[1] & 0xFFFF0000u);
    ac[4]  += __uint_as_float(u0[2] << 16);
    ac[5]  += __uint_as_float(u0[2] & 0xFFFF0000u);
    ac[6]  += __uint_as_float(u0[3] << 16);
    ac[7]  += __uint_as_float(u0[3] & 0xFFFF0000u);
    ac[8]  += __uint_as_float(u1[0] << 16);
    ac[9]  += __uint_as_float(u1[0] & 0xFFFF0000u);
    ac[10] += __uint_as_float(u1[1] << 16);
    ac[11] += __uint_as_float(u1[1] & 0xFFFF0000u);
    ac[12] += __uint_as_float(u1[2] << 16);
    ac[13] += __uint_as_float(u1[2] & 0xFFFF0000u);
    ac[14] += __uint_as_float(u1[3] << 16);
    ac[15] += __uint_as_float(u1[3] & 0xFFFF0000u);
}

// ====== fused layer: gather (4-wave split) + LDS reduce + MFMA dense ========
// R4 structure; gather-side loads are NONTEMPORAL (no L1 reuse exists for the
// random row stream or the once-streamed sorted_src).
__global__ void __launch_bounds__(256)
fused_layer(const unsigned short* __restrict__ xb,     // input features (bf16)
            const int* __restrict__ row_ptr,
            const int* __restrict__ sorted_src,
            const int* __restrict__ nperm,
            const unsigned short* __restrict__ Bt,     // [2][64][128] bf16
            const float* __restrict__ bias,
            float* __restrict__ out_f32,
            unsigned short* __restrict__ out_bf16,     // ping-pong output
            int n_nodes, int E, int last) {
    __shared__ float red[4][16][68];    // +4 float pad: <=4-way bank conflicts
    __shared__ int snode[16];           // tile slot -> node id

    int lane = threadIdx.x & 63;
    int w    = threadIdx.x >> 6;        // wave id = edge-subset + out quadrant
    int ln15 = lane & 15;
    int lhi  = lane >> 4;

    int node0 = blockIdx.x << 4;
    int slot  = node0 + ln15;
    int scl   = min(slot, n_nodes - 1);
    int node  = nperm[scl];
    if (lane < 16) snode[lane] = node;  // all waves write same values (benign)

    int beg = row_ptr[node];
    int end = row_ptr[node + 1];
    if (slot >= n_nodes) end = beg;
    int deg = end - beg;

    // tile max degree (reduce over ln15 bits; same result in each lhi group)
    int md = deg;
    md = max(md, __shfl_xor(md, 1));
    md = max(md, __shfl_xor(md, 2));
    md = max(md, __shfl_xor(md, 4));
    md = max(md, __shfl_xor(md, 8));

    float ac[16];
#pragma unroll
    for (int t = 0; t < 16; ++t) ac[t] = 0.f;

    const int Em1 = E - 1;
    int p = w;
    // branchless ILP-2: edges at positions p and p+4 of this node's list
    for (; p + 4 < md; p += 8) {
        int cA = min(beg + p,     Em1);
        int cB = min(beg + p + 4, Em1);
        int sA = __builtin_nontemporal_load(&sorted_src[cA]);
        int sB = __builtin_nontemporal_load(&sorted_src[cB]);
        const unsigned short* rA = xb + (((size_t)(unsigned)sA) << 6) + (lhi << 3);
        const unsigned short* rB = xb + (((size_t)(unsigned)sB) << 6) + (lhi << 3);
        uivec4 a0 = __builtin_nontemporal_load(reinterpret_cast<const uivec4*>(rA));
        uivec4 a1 = __builtin_nontemporal_load(reinterpret_cast<const uivec4*>(rA + 32));
        uivec4 b0 = __builtin_nontemporal_load(reinterpret_cast<const uivec4*>(rB));
        uivec4 b1 = __builtin_nontemporal_load(reinterpret_cast<const uivec4*>(rB + 32));
        if (p < deg)     acc16(ac, a0, a1);
        if (p + 4 < deg) acc16(ac, b0, b1);
    }
    for (; p < md; p += 4) {
        int cA = min(beg + p, Em1);
        int sA = __builtin_nontemporal_load(&sorted_src[cA]);
        const unsigned short* rA = xb + (((size_t)(unsigned)sA) << 6) + (lhi << 3);
        uivec4 a0 = __builtin_nontemporal_load(reinterpret_cast<const uivec4*>(rA));
        uivec4 a1 = __builtin_nontemporal_load(reinterpret_cast<const uivec4*>(rA + 32));
        if (p < deg) acc16(ac, a0, a1);
    }

    // ---- write partials to LDS ----
    int f0 = lhi << 3;
    *reinterpret_cast<float4*>(&red[w][ln15][f0])      = make_float4(ac[0], ac[1], ac[2], ac[3]);
    *reinterpret_cast<float4*>(&red[w][ln15][f0 + 4])  = make_float4(ac[4], ac[5], ac[6], ac[7]);
    *reinterpret_cast<float4*>(&red[w][ln15][32 + f0]) = make_float4(ac[8], ac[9], ac[10], ac[11]);
    *reinterpret_cast<float4*>(&red[w][ln15][36 + f0]) = make_float4(ac[12], ac[13], ac[14], ac[15]);

    // ---- B fragments for this wave's output quadrant (nf = w) ----
    bf16x8 Bf[2][4];
    {
        const unsigned short* bp = Bt + ((size_t)(w * 16 + ln15)) * 128 + (lhi << 3);
#pragma unroll
        for (int pp = 0; pp < 2; ++pp)
#pragma unroll
            for (int kc = 0; kc < 4; ++kc)
                Bf[pp][kc] = *reinterpret_cast<const bf16x8*>(bp + pp * 8192 + kc * 32);
    }
    // self row (A-frags for x)
    const unsigned short* xr = xb + (((size_t)(unsigned)node) << 6) + (lhi << 3);
    bf16x8 A0 = *reinterpret_cast<const bf16x8*>(xr);
    bf16x8 A1 = *reinterpret_cast<const bf16x8*>(xr + 32);
    float bb = bias[w * 16 + ln15];

    __syncthreads();

    // ---- reduce partials across the 4 waves ----
    float s[16];
#pragma unroll
    for (int t = 0; t < 16; ++t) s[t] = 0.f;
#pragma unroll
    for (int ww = 0; ww < 4; ++ww) {
        float4 r0 = *reinterpret_cast<const float4*>(&red[ww][ln15][f0]);
        float4 r1 = *reinterpret_cast<const float4*>(&red[ww][ln15][f0 + 4]);
        float4 r2 = *reinterpret_cast<const float4*>(&red[ww][ln15][32 + f0]);
        float4 r3 = *reinterpret_cast<const float4*>(&red[ww][ln15][36 + f0]);
        s[0]  += r0.x; s[1]  += r0.y; s[2]  += r0.z; s[3]  += r0.w;
        s[4]  += r1.x; s[5]  += r1.y; s[6]  += r1.z; s[7]  += r1.w;
        s[8]  += r2.x; s[9]  += r2.y; s[10] += r2.z; s[11] += r2.w;
        s[12] += r3.x; s[13] += r3.y; s[14] += r3.z; s[15] += r3.w;
    }
    // agg A-frags (bf16 round, same rounding point as unfused version)
    bf16x8 A2, A3;
#pragma unroll
    for (int t = 0; t < 8; ++t) A2[t] = (short)f2bf(s[t]);
#pragma unroll
    for (int t = 0; t < 8; ++t) A3[t] = (short)f2bf(s[8 + t]);

    // ---- MFMA: C quadrant [16 nodes][cols w*16..+15], K=128, hi+lo pass ----
    f32x4 c = {0.f, 0.f, 0.f, 0.f};
    c = __builtin_amdgcn_mfma_f32_16x16x32_bf16(A0, Bf[0][0], c, 0, 0, 0);
    c = __builtin_amdgcn_mfma_f32_16x16x32_bf16(A0, Bf[1][0], c, 0, 0, 0);
    c = __builtin_amdgcn_mfma_f32_16x16x32_bf16(A1, Bf[0][1], c, 0, 0, 0);
    c = __builtin_amdgcn_mfma_f32_16x16x32_bf16(A1, Bf[1][1], c, 0, 0, 0);
    c = __builtin_amdgcn_mfma_f32_16x16x32_bf16(A2, Bf[0][2], c, 0, 0, 0);
    c = __builtin_amdgcn_mfma_f32_16x16x32_bf16(A2, Bf[1][2], c, 0, 0, 0);
    c = __builtin_amdgcn_mfma_f32_16x16x32_bf16(A3, Bf[0][3], c, 0, 0, 0);
    c = __builtin_amdgcn_mfma_f32_16x16x32_bf16(A3, Bf[1][3], c, 0, 0, 0);

    // C/D: col = ln15 (+16*w), tile slot row = node0 + lhi*4 + r -> snode[]
    int colo = w * 16 + ln15;
    if (last) {
#pragma unroll
        for (int r = 0; r < 4; ++r) {
            int sl = lhi * 4 + r;
            if (node0 + sl < n_nodes) {
                int nr = snode[sl];
                out_f32[((size_t)(unsigned)nr << 6) + colo] = c[r] + bb;
            }
        }
    } else {
#pragma unroll
        for (int r = 0; r < 4; ++r) {
            int sl = lhi * 4 + r;
            if (node0 + sl < n_nodes) {
                int nr = snode[sl];
                out_bf16[((size_t)(unsigned)nr << 6) + colo] = f2bf(fmaxf(c[r] + bb, 0.f));
            }
        }
    }
}

// ================= fallback (atomic path, fp32-exact) =======================
__global__ void scatter_kernel(const float* __restrict__ x,
                               const int* __restrict__ src,
                               const int* __restrict__ dst,
                               float* __restrict__ agg, int n_edges) {
    int e = blockIdx.x * (blockDim.x >> 6) + (threadIdx.x >> 6);
    int lane = threadIdx.x & 63;
    if (e >= n_edges) return;
    float v = x[(size_t)src[e] * D + lane];
    unsafeAtomicAdd(&agg[(size_t)dst[e] * D + lane], v);
}

__global__ void dense_kernel(const float* __restrict__ xin,
                             const float* __restrict__ agg,
                             const float* __restrict__ Wself,
                             const float* __restrict__ Wmsg,
                             const float* __restrict__ bias,
                             float* __restrict__ xout,
                             int n_nodes, int do_relu) {
    __shared__ float Ws[D * D];
    __shared__ float Wm[D * D];
    for (int i = threadIdx.x; i < D * D; i += blockDim.x) {
        Ws[i] = Wself[i];
        Wm[i] = Wmsg[i];
    }
    __syncthreads();
    int lane = threadIdx.x & 63;
    int wave = threadIdx.x >> 6;
    int wpb = blockDim.x >> 6;
    float bj = bias[lane];
    for (int n = blockIdx.x * wpb + wave; n < n_nodes; n += gridDim.x * wpb) {
        float xv = xin[(size_t)n * D + lane];
        float av = agg[(size_t)n * D + lane];
        float acc = bj;
#pragma unroll
        for (int k = 0; k < D; ++k) {
            acc += __shfl(xv, k, 64) * Ws[k * D + lane]
                 + __shfl(av, k, 64) * Wm[k * D + lane];
        }
        if (do_relu) acc = fmaxf(acc, 0.f);
        xout[(size_t)n * D + lane] = acc;
    }
}

// ============================================================================
extern "C" void kernel_launch(void* const* d_in, const int* in_sizes, int n_in,
                              void* d_out, int out_size, void* d_ws, size_t ws_size,
                              hipStream_t stream) {
    const float* x0    = (const float*)d_in[0];
    const int*   ei    = (const int*)d_in[1];
    const float* Wmsg  = (const float*)d_in[2];
    const float* Wself = (const float*)d_in[3];
    const float* bias  = (const float*)d_in[4];
    float* out = (float*)d_out;

    const int N = in_sizes[0] / D;         // 50000
    const int E = in_sizes[1] / 2;         // 800000
    const int n_layers = in_sizes[4] / D;  // 3

    const int* src = ei;
    const int* dst = ei + E;
    const size_t NB = (size_t)N * D * sizeof(float);

    const int NBB = (N + 255) / 256;
    const size_t BtB = (size_t)n_layers * 2 * D * 2 * D * 2;  // hi/lo weights, bf16
    const size_t need = (size_t)N * D * 2          // Xb
                      + (size_t)N * D * 2          // Xb2 (ping-pong)
                      + BtB                        // Bt (MFMA weights)
                      + (size_t)E * 4              // sorted_src
                      + (size_t)E * 4              // rank
                      + (size_t)(N + 1) * 4        // row_ptr
                      + (size_t)N * 4              // deg
                      + (size_t)N * 4              // nperm
                      + 1024 * 4 * 2               // dhist + dbase
                      + (size_t)NBB * 4 * 2 + 256; // bsum + boff + slack

    if (ws_size >= need && NBB <= 1024) {
        char* p = (char*)d_ws;
        unsigned short* Xb   = (unsigned short*)p;  p += (size_t)N * D * 2;
        unsigned short* Xb2  = (unsigned short*)p;  p += (size_t)N * D * 2;
        unsigned short* Bt   = (unsigned short*)p;  p += BtB;
        int* sorted_src      = (int*)p;             p += (size_t)E * 4;
        int* rank            = (int*)p;             p += (size_t)E * 4;
        int* row_ptr         = (int*)p;             p += (size_t)(N + 1) * 4;
        int* deg             = (int*)p;             p += (size_t)N * 4;
        int* nperm           = (int*)p;             p += (size_t)N * 4;
        int* dhist           = (int*)p;             p += 1024 * 4;
        int* dbase           = (int*)p;             p += 1024 * 4;
        int* bsum            = (int*)p;             p += (size_t)NBB * 4;
        int* boff            = (int*)p;

        {
            // prep: zero deg/dhist + convert x -> bf16 + build Bt (one dispatch)
            int total = N * D;
            int nthr = (total + 3) / 4;
            prep_kernel<<<(nthr + 255) / 256, 256, 0, stream>>>(
                x0, Xb, total, deg, N, Wself, Wmsg, Bt, n_layers, dhist);

            int threads = 256;
            int nthr8 = (E + 7) / 8;
            int blocks = (nthr8 + threads - 1) / threads;
            hist_rank_kernel<<<blocks, threads, 0, stream>>>(dst, deg, rank, E);
            scan_k1<<<NBB, 256, 0, stream>>>(deg, bsum, N, dhist);
            scan_k2<<<1, 1024, 0, stream>>>(bsum, boff, NBB, dhist, dbase);
            scan_k3_perm<<<NBB, 256, 0, stream>>>(deg, boff, row_ptr, N, dbase, nperm);
            perm_rank_kernel<<<blocks, threads, 0, stream>>>(src, dst, rank, row_ptr,
                                                             sorted_src, E);
        }

        const int dtiles = (N + 15) >> 4;        // 16-node tiles (3125)
        const unsigned short* in_b = Xb;
        unsigned short* out_b = Xb2;

        for (int layer = 0; layer < n_layers; ++layer) {
            fused_layer<<<dtiles, 256, 0, stream>>>(
                in_b, row_ptr, sorted_src, nperm,
                Bt + (size_t)layer * 2 * D * 2 * D,
                bias + (size_t)layer * D,
                out, out_b, N, E, (layer == n_layers - 1) ? 1 : 0);
            // ping-pong
            const unsigned short* t = in_b;
            in_b = out_b;
            out_b = (unsigned short*)t;
        }
    } else {
        // fallback: fp32 atomic path
        float* agg = (float*)d_ws;
        const int EPB = 256 / 64;
        const int scatter_blocks = (E + EPB - 1) / EPB;
        for (int layer = 0; layer < n_layers; ++layer) {
            hipMemsetAsync(agg, 0, NB, stream);
            const float* xin = (layer == 0) ? x0 : out;
            scatter_kernel<<<scatter_blocks, 256, 0, stream>>>(xin, src, dst, agg, E);
            dense_kernel<<<1024, 256, 0, stream>>>(
                xin, agg,
                Wself + (size_t)layer * D * D,
                Wmsg  + (size_t)layer * D * D,
                bias  + (size_t)layer * D,
                out, N, (layer < n_layers - 1) ? 1 : 0);
        }
    }
}

// Round 8
// 258.638 us; speedup vs baseline: 1.0652x; 1.0652x over previous
//
#include <hip/hip_runtime.h>

#define D 64

// ---- bf16 helpers (RNE), raw ushort storage ------------------------------
__device__ __forceinline__ unsigned short f2bf(float f) {
    unsigned u = __float_as_uint(f);
    unsigned r = (u + 0x7FFFu + ((u >> 16) & 1u)) >> 16;
    return (unsigned short)r;
}
__device__ __forceinline__ float bf2f(unsigned short h) {
    return __uint_as_float((unsigned)h << 16);
}

typedef __attribute__((ext_vector_type(8))) short bf16x8;
typedef __attribute__((ext_vector_type(4))) float f32x4;
typedef __attribute__((ext_vector_type(4))) unsigned uivec4;

// ============ prep: zero deg/dhist + convert x (fp32) -> Xb (bf16) ==========
__global__ void prep_kernel(const float* __restrict__ x, unsigned short* __restrict__ xb,
                            int total, int* __restrict__ deg, int N,
                            const float* __restrict__ Wself,
                            const float* __restrict__ Wmsg,
                            unsigned short* __restrict__ Bt, int n_layers,
                            int* __restrict__ dhist) {
    int i = blockIdx.x * blockDim.x + threadIdx.x;
    if (i < N) deg[i] = 0;
    if (i < 1024) dhist[i] = 0;
    // weight transpose + hi/lo split (tiny: n_layers*64*128 threads)
    int wtotal = n_layers * D * 2 * D;   // l * 8192
    if (i < wtotal) {
        int k = i & 127;
        int n = (i >> 7) & 63;
        int l = i >> 13;
        float w = (k < D) ? Wself[(size_t)l * D * D + k * D + n]
                          : Wmsg [(size_t)l * D * D + (k - D) * D + n];
        unsigned short hi = f2bf(w);
        unsigned short lo = f2bf(w - bf2f(hi));
        size_t base = (size_t)l * 2 * D * 2 * D;     // l * 16384
        Bt[base + (size_t)n * 128 + k] = hi;
        Bt[base + 8192 + (size_t)n * 128 + k] = lo;
    }
    int base = i * 4;
    if (base + 4 <= total) {
        float4 v = *reinterpret_cast<const float4*>(x + base);
        ushort4 o;
        o.x = f2bf(v.x); o.y = f2bf(v.y); o.z = f2bf(v.z); o.w = f2bf(v.w);
        *reinterpret_cast<ushort4*>(xb + base) = o;
    } else if (base < total) {
        for (int k = base; k < total; ++k) xb[k] = f2bf(x[k]);
    }
}

// ================= CSR build: hist captures per-edge rank ===================
__global__ void hist_rank_kernel(const int* __restrict__ dst, int* __restrict__ deg,
                                 int* __restrict__ rank, int E) {
    int i = blockIdx.x * blockDim.x + threadIdx.x;
    int base = i * 8;
    if (base + 8 <= E) {
        int4 d0 = *reinterpret_cast<const int4*>(dst + base);
        int4 d1 = *reinterpret_cast<const int4*>(dst + base + 4);
        int4 r0, r1;                       // 8 independent atomic chains
        r0.x = atomicAdd(&deg[d0.x], 1);
        r0.y = atomicAdd(&deg[d0.y], 1);
        r0.z = atomicAdd(&deg[d0.z], 1);
        r0.w = atomicAdd(&deg[d0.w], 1);
        r1.x = atomicAdd(&deg[d1.x], 1);
        r1.y = atomicAdd(&deg[d1.y], 1);
        r1.z = atomicAdd(&deg[d1.z], 1);
        r1.w = atomicAdd(&deg[d1.w], 1);
        *reinterpret_cast<int4*>(rank + base) = r0;
        *reinterpret_cast<int4*>(rank + base + 4) = r1;
    } else {
        for (int e = base; e < E; ++e) rank[e] = atomicAdd(&deg[dst[e]], 1);
    }
}

// scan_k1: block sums of deg + degree histogram (LDS-privatized)
__global__ void scan_k1(const int* __restrict__ deg, int* __restrict__ bsum, int n,
                        int* __restrict__ dhist) {
    __shared__ int sh[256];
    __shared__ int lh[1024];
    int t = threadIdx.x;
    for (int i = t; i < 1024; i += 256) lh[i] = 0;
    __syncthreads();
    int g = blockIdx.x * 256 + t;
    int v = (g < n) ? deg[g] : 0;
    if (g < n) atomicAdd(&lh[min(v, 1023)], 1);
    sh[t] = v;
    __syncthreads();
    for (int off = 1; off < 256; off <<= 1) {
        int u = (t >= off) ? sh[t - off] : 0;
        __syncthreads();
        sh[t] += u;
        __syncthreads();
    }
    if (t == 255) bsum[blockIdx.x] = sh[255];
    __syncthreads();
    for (int i = t; i < 1024; i += 256) {
        int c = lh[i];
        if (c) atomicAdd(&dhist[i], c);
    }
}

// scan_k2: scan block sums + suffix-scan of dhist (descending-degree bases)
__global__ void scan_k2(const int* __restrict__ bsum, int* __restrict__ boff, int nb,
                        const int* __restrict__ dhist, int* __restrict__ dbase) {
    __shared__ int sh[1024];
    int t = threadIdx.x;
    int v = (t < nb) ? bsum[t] : 0;
    sh[t] = v;
    __syncthreads();
    for (int off = 1; off < 1024; off <<= 1) {
        int u = (t >= off) ? sh[t - off] : 0;
        __syncthreads();
        sh[t] += u;
        __syncthreads();
    }
    if (t < nb) boff[t] = sh[t] - v;
    __syncthreads();
    int rb = 1023 - t;
    int dv = dhist[rb];
    sh[t] = dv;
    __syncthreads();
    for (int off = 1; off < 1024; off <<= 1) {
        int u = (t >= off) ? sh[t - off] : 0;
        __syncthreads();
        sh[t] += u;
        __syncthreads();
    }
    dbase[rb] = sh[t] - dv;
}

// scan_k3 + perm_nodes fused: same grid, both consume deg + precomputed bases.
// Writes row_ptr (exclusive scan) AND nperm (descending-degree counting sort).
__global__ void scan_k3_perm(const int* __restrict__ deg, const int* __restrict__ boff,
                             int* __restrict__ row_ptr, int n,
                             int* __restrict__ dbase, int* __restrict__ nperm) {
    __shared__ int sh[256];
    __shared__ int lh[1024];
    __shared__ int lbase[1024];
    int t = threadIdx.x;
    for (int i = t; i < 1024; i += 256) lh[i] = 0;
    int g = blockIdx.x * 256 + t;
    int v = (g < n) ? deg[g] : 0;
    sh[t] = v;
    __syncthreads();
    for (int off = 1; off < 256; off <<= 1) {
        int u = (t >= off) ? sh[t - off] : 0;
        __syncthreads();
        sh[t] += u;
        __syncthreads();
    }
    if (g < n) {
        int excl = sh[t] - v + boff[blockIdx.x];
        row_ptr[g] = excl;
        if (g == n - 1) row_ptr[n] = excl + v;
    }
    // counting-sort part (lh zeroing was synced by the scan's barriers)
    int b = 0, lrank = 0;
    if (g < n) {
        b = min(v, 1023);
        lrank = atomicAdd(&lh[b], 1);
    }
    __syncthreads();
    for (int i = t; i < 1024; i += 256) {
        int c = lh[i];
        lbase[i] = c ? atomicAdd(&dbase[i], c) : 0;
    }
    __syncthreads();
    if (g < n) nperm[lbase[b] + lrank] = g;
}

// atomic-free permutation: pos = row_ptr[dst] + rank
__global__ void perm_rank_kernel(const int* __restrict__ src, const int* __restrict__ dst,
                                 const int* __restrict__ rank, const int* __restrict__ row_ptr,
                                 int* __restrict__ sorted_src, int E) {
    int i = blockIdx.x * blockDim.x + threadIdx.x;
    int base = i * 8;
    if (base + 8 <= E) {
        int4 d0 = *reinterpret_cast<const int4*>(dst + base);
        int4 d1 = *reinterpret_cast<const int4*>(dst + base + 4);
        int4 s0 = *reinterpret_cast<const int4*>(src + base);
        int4 s1 = *reinterpret_cast<const int4*>(src + base + 4);
        int4 r0 = *reinterpret_cast<const int4*>(rank + base);
        int4 r1 = *reinterpret_cast<const int4*>(rank + base + 4);
        int p0 = row_ptr[d0.x] + r0.x;
        int p1 = row_ptr[d0.y] + r0.y;
        int p2 = row_ptr[d0.z] + r0.z;
        int p3 = row_ptr[d0.w] + r0.w;
        int p4 = row_ptr[d1.x] + r1.x;
        int p5 = row_ptr[d1.y] + r1.y;
        int p6 = row_ptr[d1.z] + r1.z;
        int p7 = row_ptr[d1.w] + r1.w;
        __builtin_nontemporal_store(s0.x, &sorted_src[p0]);
        __builtin_nontemporal_store(s0.y, &sorted_src[p1]);
        __builtin_nontemporal_store(s0.z, &sorted_src[p2]);
        __builtin_nontemporal_store(s0.w, &sorted_src[p3]);
        __builtin_nontemporal_store(s1.x, &sorted_src[p4]);
        __builtin_nontemporal_store(s1.y, &sorted_src[p5]);
        __builtin_nontemporal_store(s1.z, &sorted_src[p6]);
        __builtin_nontemporal_store(s1.w, &sorted_src[p7]);
    } else {
        for (int e = base; e < E; ++e)
            sorted_src[row_ptr[dst[e]] + rank[e]] = src[e];
    }
}

// ---- accumulate 16 bf16 feats (2 x uivec4) into fp32 lanes -----------------
__device__ __forceinline__ void acc16(float* ac, uivec4 u0, uivec4 u1) {
    ac[0]  += __uint_as_float(u0[0] << 16);
    ac[1]  += __uint_as_float(u0[0] & 0xFFFF0000u);
    ac[2]  += __uint_as_float(u0[1] << 16);
    ac[3]  += __uint_as_float(u0[1] & 0xFFFF0000u);
    ac[4]  += __uint_as_float(u0[2] << 16);
    ac[5]  += __uint_as_float(u0[2] & 0xFFFF0000u);
    ac[6]  += __uint_as_float(u0[3] << 16);
    ac[7]  += __uint_as_float(u0[3] & 0xFFFF0000u);
    ac[8]  += __uint_as_float(u1[0] << 16);
    ac[9]  += __uint_as_float(u1[0] & 0xFFFF0000u);
    ac[10] += __uint_as_float(u1[1] << 16);
    ac[11] += __uint_as_float(u1[1] & 0xFFFF0000u);
    ac[12] += __uint_as_float(u1[2] << 16);
    ac[13] += __uint_as_float(u1[2] & 0xFFFF0000u);
    ac[14] += __uint_as_float(u1[3] << 16);
    ac[15] += __uint_as_float(u1[3] & 0xFFFF0000u);
}

// ====== fused layer: gather (4-wave split) + LDS reduce + MFMA dense ========
// Block = 4 waves = one 16-node tile (nperm: degree-homogeneous tiles).
// Gather loop batches 4 independent index loads then 8 independent row loads
// (12 outstanding, one dependency round per 4 positions) -> max MLP.
// Accumulation stays in ascending position order per lane (bitwise-identical).
__global__ void __launch_bounds__(256)
fused_layer(const unsigned short* __restrict__ xb,     // input features (bf16)
            const int* __restrict__ row_ptr,
            const int* __restrict__ sorted_src,
            const int* __restrict__ nperm,
            const unsigned short* __restrict__ Bt,     // [2][64][128] bf16
            const float* __restrict__ bias,
            float* __restrict__ out_f32,
            unsigned short* __restrict__ out_bf16,     // ping-pong output
            int n_nodes, int E, int last) {
    __shared__ float red[4][16][68];    // +4 float pad: <=4-way bank conflicts
    __shared__ int snode[16];           // tile slot -> node id

    int lane = threadIdx.x & 63;
    int w    = threadIdx.x >> 6;        // wave id = edge-subset + out quadrant
    int ln15 = lane & 15;
    int lhi  = lane >> 4;

    int node0 = blockIdx.x << 4;
    int slot  = node0 + ln15;
    int scl   = min(slot, n_nodes - 1);
    int node  = nperm[scl];
    if (lane < 16) snode[lane] = node;  // all waves write same values (benign)

    int beg = row_ptr[node];
    int end = row_ptr[node + 1];
    if (slot >= n_nodes) end = beg;
    int deg = end - beg;

    // tile max degree (reduce over ln15 bits; same result in each lhi group)
    int md = deg;
    md = max(md, __shfl_xor(md, 1));
    md = max(md, __shfl_xor(md, 2));
    md = max(md, __shfl_xor(md, 4));
    md = max(md, __shfl_xor(md, 8));

    float ac[16];
#pragma unroll
    for (int t = 0; t < 16; ++t) ac[t] = 0.f;

    const int Em1 = E - 1;
    // ILP-4: positions {pos, pos+4, pos+8, pos+12}; all idx loads issued
    // before any row load (independent batches -> 12 loads in flight).
    for (int pos = w; pos < md; pos += 16) {
        int p1 = pos + 4, p2 = pos + 8, p3 = pos + 12;
        int c0 = min(beg + pos, Em1);
        int c1 = min(beg + p1,  Em1);
        int c2 = min(beg + p2,  Em1);
        int c3 = min(beg + p3,  Em1);
        int s0 = sorted_src[c0];
        int s1 = sorted_src[c1];
        int s2 = sorted_src[c2];
        int s3 = sorted_src[c3];
        const unsigned short* r0 = xb + (((size_t)(unsigned)s0) << 6) + (lhi << 3);
        const unsigned short* r1 = xb + (((size_t)(unsigned)s1) << 6) + (lhi << 3);
        const unsigned short* r2 = xb + (((size_t)(unsigned)s2) << 6) + (lhi << 3);
        const unsigned short* r3 = xb + (((size_t)(unsigned)s3) << 6) + (lhi << 3);
        uivec4 a0 = *reinterpret_cast<const uivec4*>(r0);
        uivec4 a1 = *reinterpret_cast<const uivec4*>(r0 + 32);
        uivec4 b0 = *reinterpret_cast<const uivec4*>(r1);
        uivec4 b1 = *reinterpret_cast<const uivec4*>(r1 + 32);
        uivec4 c0v = *reinterpret_cast<const uivec4*>(r2);
        uivec4 c1v = *reinterpret_cast<const uivec4*>(r2 + 32);
        uivec4 d0 = *reinterpret_cast<const uivec4*>(r3);
        uivec4 d1 = *reinterpret_cast<const uivec4*>(r3 + 32);
        if (pos < deg) acc16(ac, a0, a1);
        if (p1  < deg) acc16(ac, b0, b1);
        if (p2  < deg) acc16(ac, c0v, c1v);
        if (p3  < deg) acc16(ac, d0, d1);
    }

    // ---- write partials to LDS ----
    int f0 = lhi << 3;
    *reinterpret_cast<float4*>(&red[w][ln15][f0])      = make_float4(ac[0], ac[1], ac[2], ac[3]);
    *reinterpret_cast<float4*>(&red[w][ln15][f0 + 4])  = make_float4(ac[4], ac[5], ac[6], ac[7]);
    *reinterpret_cast<float4*>(&red[w][ln15][32 + f0]) = make_float4(ac[8], ac[9], ac[10], ac[11]);
    *reinterpret_cast<float4*>(&red[w][ln15][36 + f0]) = make_float4(ac[12], ac[13], ac[14], ac[15]);

    // ---- B fragments for this wave's output quadrant (nf = w) ----
    bf16x8 Bf[2][4];
    {
        const unsigned short* bp = Bt + ((size_t)(w * 16 + ln15)) * 128 + (lhi << 3);
#pragma unroll
        for (int pp = 0; pp < 2; ++pp)
#pragma unroll
            for (int kc = 0; kc < 4; ++kc)
                Bf[pp][kc] = *reinterpret_cast<const bf16x8*>(bp + pp * 8192 + kc * 32);
    }
    // self row (A-frags for x)
    const unsigned short* xr = xb + (((size_t)(unsigned)node) << 6) + (lhi << 3);
    bf16x8 A0 = *reinterpret_cast<const bf16x8*>(xr);
    bf16x8 A1 = *reinterpret_cast<const bf16x8*>(xr + 32);
    float bb = bias[w * 16 + ln15];

    __syncthreads();

    // ---- reduce partials across the 4 waves ----
    float s[16];
#pragma unroll
    for (int t = 0; t < 16; ++t) s[t] = 0.f;
#pragma unroll
    for (int ww = 0; ww < 4; ++ww) {
        float4 r0 = *reinterpret_cast<const float4*>(&red[ww][ln15][f0]);
        float4 r1 = *reinterpret_cast<const float4*>(&red[ww][ln15][f0 + 4]);
        float4 r2 = *reinterpret_cast<const float4*>(&red[ww][ln15][32 + f0]);
        float4 r3 = *reinterpret_cast<const float4*>(&red[ww][ln15][36 + f0]);
        s[0]  += r0.x; s[1]  += r0.y; s[2]  += r0.z; s[3]  += r0.w;
        s[4]  += r1.x; s[5]  += r1.y; s[6]  += r1.z; s[7]  += r1.w;
        s[8]  += r2.x; s[9]  += r2.y; s[10] += r2.z; s[11] += r2.w;
        s[12] += r3.x; s[13] += r3.y; s[14] += r3.z; s[15] += r3.w;
    }
    // agg A-frags (bf16 round, same rounding point as unfused version)
    bf16x8 A2, A3;
#pragma unroll
    for (int t = 0; t < 8; ++t) A2[t] = (short)f2bf(s[t]);
#pragma unroll
    for (int t = 0; t < 8; ++t) A3[t] = (short)f2bf(s[8 + t]);

    // ---- MFMA: C quadrant [16 nodes][cols w*16..+15], K=128, hi+lo pass ----
    f32x4 c = {0.f, 0.f, 0.f, 0.f};
    c = __builtin_amdgcn_mfma_f32_16x16x32_bf16(A0, Bf[0][0], c, 0, 0, 0);
    c = __builtin_amdgcn_mfma_f32_16x16x32_bf16(A0, Bf[1][0], c, 0, 0, 0);
    c = __builtin_amdgcn_mfma_f32_16x16x32_bf16(A1, Bf[0][1], c, 0, 0, 0);
    c = __builtin_amdgcn_mfma_f32_16x16x32_bf16(A1, Bf[1][1], c, 0, 0, 0);
    c = __builtin_amdgcn_mfma_f32_16x16x32_bf16(A2, Bf[0][2], c, 0, 0, 0);
    c = __builtin_amdgcn_mfma_f32_16x16x32_bf16(A2, Bf[1][2], c, 0, 0, 0);
    c = __builtin_amdgcn_mfma_f32_16x16x32_bf16(A3, Bf[0][3], c, 0, 0, 0);
    c = __builtin_amdgcn_mfma_f32_16x16x32_bf16(A3, Bf[1][3], c, 0, 0, 0);

    // C/D: col = ln15 (+16*w), tile slot row = node0 + lhi*4 + r -> snode[]
    int colo = w * 16 + ln15;
    if (last) {
#pragma unroll
        for (int r = 0; r < 4; ++r) {
            int sl = lhi * 4 + r;
            if (node0 + sl < n_nodes) {
                int nr = snode[sl];
                out_f32[((size_t)(unsigned)nr << 6) + colo] = c[r] + bb;
            }
        }
    } else {
#pragma unroll
        for (int r = 0; r < 4; ++r) {
            int sl = lhi * 4 + r;
            if (node0 + sl < n_nodes) {
                int nr = snode[sl];
                out_bf16[((size_t)(unsigned)nr << 6) + colo] = f2bf(fmaxf(c[r] + bb, 0.f));
            }
        }
    }
}

// ================= fallback (atomic path, fp32-exact) =======================
__global__ void scatter_kernel(const float* __restrict__ x,
                               const int* __restrict__ src,
                               const int* __restrict__ dst,
                               float* __restrict__ agg, int n_edges) {
    int e = blockIdx.x * (blockDim.x >> 6) + (threadIdx.x >> 6);
    int lane = threadIdx.x & 63;
    if (e >= n_edges) return;
    float v = x[(size_t)src[e] * D + lane];
    unsafeAtomicAdd(&agg[(size_t)dst[e] * D + lane], v);
}

__global__ void dense_kernel(const float* __restrict__ xin,
                             const float* __restrict__ agg,
                             const float* __restrict__ Wself,
                             const float* __restrict__ Wmsg,
                             const float* __restrict__ bias,
                             float* __restrict__ xout,
                             int n_nodes, int do_relu) {
    __shared__ float Ws[D * D];
    __shared__ float Wm[D * D];
    for (int i = threadIdx.x; i < D * D; i += blockDim.x) {
        Ws[i] = Wself[i];
        Wm[i] = Wmsg[i];
    }
    __syncthreads();
    int lane = threadIdx.x & 63;
    int wave = threadIdx.x >> 6;
    int wpb = blockDim.x >> 6;
    float bj = bias[lane];
    for (int n = blockIdx.x * wpb + wave; n < n_nodes; n += gridDim.x * wpb) {
        float xv = xin[(size_t)n * D + lane];
        float av = agg[(size_t)n * D + lane];
        float acc = bj;
#pragma unroll
        for (int k = 0; k < D; ++k) {
            acc += __shfl(xv, k, 64) * Ws[k * D + lane]
                 + __shfl(av, k, 64) * Wm[k * D + lane];
        }
        if (do_relu) acc = fmaxf(acc, 0.f);
        xout[(size_t)n * D + lane] = acc;
    }
}

// ============================================================================
extern "C" void kernel_launch(void* const* d_in, const int* in_sizes, int n_in,
                              void* d_out, int out_size, void* d_ws, size_t ws_size,
                              hipStream_t stream) {
    const float* x0    = (const float*)d_in[0];
    const int*   ei    = (const int*)d_in[1];
    const float* Wmsg  = (const float*)d_in[2];
    const float* Wself = (const float*)d_in[3];
    const float* bias  = (const float*)d_in[4];
    float* out = (float*)d_out;

    const int N = in_sizes[0] / D;         // 50000
    const int E = in_sizes[1] / 2;         // 800000
    const int n_layers = in_sizes[4] / D;  // 3

    const int* src = ei;
    const int* dst = ei + E;
    const size_t NB = (size_t)N * D * sizeof(float);

    const int NBB = (N + 255) / 256;
    const size_t BtB = (size_t)n_layers * 2 * D * 2 * D * 2;  // hi/lo weights, bf16
    const size_t need = (size_t)N * D * 2          // Xb
                      + (size_t)N * D * 2          // Xb2 (ping-pong)
                      + BtB                        // Bt (MFMA weights)
                      + (size_t)E * 4              // sorted_src
                      + (size_t)E * 4              // rank
                      + (size_t)(N + 1) * 4        // row_ptr
                      + (size_t)N * 4              // deg
                      + (size_t)N * 4              // nperm
                      + 1024 * 4 * 2               // dhist + dbase
                      + (size_t)NBB * 4 * 2 + 256; // bsum + boff + slack

    if (ws_size >= need && NBB <= 1024) {
        char* p = (char*)d_ws;
        unsigned short* Xb   = (unsigned short*)p;  p += (size_t)N * D * 2;
        unsigned short* Xb2  = (unsigned short*)p;  p += (size_t)N * D * 2;
        unsigned short* Bt   = (unsigned short*)p;  p += BtB;
        int* sorted_src      = (int*)p;             p += (size_t)E * 4;
        int* rank            = (int*)p;             p += (size_t)E * 4;
        int* row_ptr         = (int*)p;             p += (size_t)(N + 1) * 4;
        int* deg             = (int*)p;             p += (size_t)N * 4;
        int* nperm           = (int*)p;             p += (size_t)N * 4;
        int* dhist           = (int*)p;             p += 1024 * 4;
        int* dbase           = (int*)p;             p += 1024 * 4;
        int* bsum            = (int*)p;             p += (size_t)NBB * 4;
        int* boff            = (int*)p;

        {
            // prep: zero deg/dhist + convert x -> bf16 + build Bt (one dispatch)
            int total = N * D;
            int nthr = (total + 3) / 4;
            prep_kernel<<<(nthr + 255) / 256, 256, 0, stream>>>(
                x0, Xb, total, deg, N, Wself, Wmsg, Bt, n_layers, dhist);

            int threads = 256;
            int nthr8 = (E + 7) / 8;
            int blocks = (nthr8 + threads - 1) / threads;
            hist_rank_kernel<<<blocks, threads, 0, stream>>>(dst, deg, rank, E);
            scan_k1<<<NBB, 256, 0, stream>>>(deg, bsum, N, dhist);
            scan_k2<<<1, 1024, 0, stream>>>(bsum, boff, NBB, dhist, dbase);
            scan_k3_perm<<<NBB, 256, 0, stream>>>(deg, boff, row_ptr, N, dbase, nperm);
            perm_rank_kernel<<<blocks, threads, 0, stream>>>(src, dst, rank, row_ptr,
                                                             sorted_src, E);
        }

        const int dtiles = (N + 15) >> 4;        // 16-node tiles (3125)
        const unsigned short* in_b = Xb;
        unsigned short* out_b = Xb2;

        for (int layer = 0; layer < n_layers; ++layer) {
            fused_layer<<<dtiles, 256, 0, stream>>>(
                in_b, row_ptr, sorted_src, nperm,
                Bt + (size_t)layer * 2 * D * 2 * D,
                bias + (size_t)layer * D,
                out, out_b, N, E, (layer == n_layers - 1) ? 1 : 0);
            // ping-pong
            const unsigned short* t = in_b;
            in_b = out_b;
            out_b = (unsigned short*)t;
        }
    } else {
        // fallback: fp32 atomic path
        float* agg = (float*)d_ws;
        const int EPB = 256 / 64;
        const int scatter_blocks = (E + EPB - 1) / EPB;
        for (int layer = 0; layer < n_layers; ++layer) {
            hipMemsetAsync(agg, 0, NB, stream);
            const float* xin = (layer == 0) ? x0 : out;
            scatter_kernel<<<scatter_blocks, 256, 0, stream>>>(xin, src, dst, agg, E);
            dense_kernel<<<1024, 256, 0, stream>>>(
                xin, agg,
                Wself + (size_t)layer * D * D,
                Wmsg  + (size_t)layer * D * D,
                bias  + (size_t)layer * D,
                out, N, (layer < n_layers - 1) ? 1 : 0);
        }
    }
}

// Round 9
// 246.773 us; speedup vs baseline: 1.1164x; 1.0481x over previous
//
#include <hip/hip_runtime.h>

#define D 64

// ---- bf16 helpers (RNE), raw ushort storage ------------------------------
__device__ __forceinline__ unsigned short f2bf(float f) {
    unsigned u = __float_as_uint(f);
    unsigned r = (u + 0x7FFFu + ((u >> 16) & 1u)) >> 16;
    return (unsigned short)r;
}
__device__ __forceinline__ float bf2f(unsigned short h) {
    return __uint_as_float((unsigned)h << 16);
}

typedef __attribute__((ext_vector_type(8))) short bf16x8;
typedef __attribute__((ext_vector_type(4))) float f32x4;

// ============ prep: zero deg/dhist + convert x (fp32) -> Xb (bf16) ==========
__global__ void prep_kernel(const float* __restrict__ x, unsigned short* __restrict__ xb,
                            int total, int* __restrict__ deg, int N,
                            const float* __restrict__ Wself,
                            const float* __restrict__ Wmsg,
                            unsigned short* __restrict__ Bt, int n_layers,
                            int* __restrict__ dhist) {
    int i = blockIdx.x * blockDim.x + threadIdx.x;
    if (i < N) deg[i] = 0;
    if (i < 1024) dhist[i] = 0;
    // weight transpose + hi/lo split (tiny: n_layers*64*128 threads)
    int wtotal = n_layers * D * 2 * D;   // l * 8192
    if (i < wtotal) {
        int k = i & 127;
        int n = (i >> 7) & 63;
        int l = i >> 13;
        float w = (k < D) ? Wself[(size_t)l * D * D + k * D + n]
                          : Wmsg [(size_t)l * D * D + (k - D) * D + n];
        unsigned short hi = f2bf(w);
        unsigned short lo = f2bf(w - bf2f(hi));
        size_t base = (size_t)l * 2 * D * 2 * D;     // l * 16384
        Bt[base + (size_t)n * 128 + k] = hi;
        Bt[base + 8192 + (size_t)n * 128 + k] = lo;
    }
    int base = i * 4;
    if (base + 4 <= total) {
        float4 v = *reinterpret_cast<const float4*>(x + base);
        ushort4 o;
        o.x = f2bf(v.x); o.y = f2bf(v.y); o.z = f2bf(v.z); o.w = f2bf(v.w);
        *reinterpret_cast<ushort4*>(xb + base) = o;
    } else if (base < total) {
        for (int k = base; k < total; ++k) xb[k] = f2bf(x[k]);
    }
}

// ================= CSR build: hist captures per-edge rank ===================
__global__ void hist_rank_kernel(const int* __restrict__ dst, int* __restrict__ deg,
                                 int* __restrict__ rank, int E) {
    int i = blockIdx.x * blockDim.x + threadIdx.x;
    int base = i * 8;
    if (base + 8 <= E) {
        int4 d0 = *reinterpret_cast<const int4*>(dst + base);
        int4 d1 = *reinterpret_cast<const int4*>(dst + base + 4);
        int4 r0, r1;                       // 8 independent atomic chains
        r0.x = atomicAdd(&deg[d0.x], 1);
        r0.y = atomicAdd(&deg[d0.y], 1);
        r0.z = atomicAdd(&deg[d0.z], 1);
        r0.w = atomicAdd(&deg[d0.w], 1);
        r1.x = atomicAdd(&deg[d1.x], 1);
        r1.y = atomicAdd(&deg[d1.y], 1);
        r1.z = atomicAdd(&deg[d1.z], 1);
        r1.w = atomicAdd(&deg[d1.w], 1);
        *reinterpret_cast<int4*>(rank + base) = r0;
        *reinterpret_cast<int4*>(rank + base + 4) = r1;
    } else {
        for (int e = base; e < E; ++e) rank[e] = atomicAdd(&deg[dst[e]], 1);
    }
}

// scan_k1: block sums of deg + degree histogram (LDS-privatized)
__global__ void scan_k1(const int* __restrict__ deg, int* __restrict__ bsum, int n,
                        int* __restrict__ dhist) {
    __shared__ int sh[256];
    __shared__ int lh[1024];
    int t = threadIdx.x;
    for (int i = t; i < 1024; i += 256) lh[i] = 0;
    __syncthreads();
    int g = blockIdx.x * 256 + t;
    int v = (g < n) ? deg[g] : 0;
    if (g < n) atomicAdd(&lh[min(v, 1023)], 1);
    sh[t] = v;
    __syncthreads();
    for (int off = 1; off < 256; off <<= 1) {
        int u = (t >= off) ? sh[t - off] : 0;
        __syncthreads();
        sh[t] += u;
        __syncthreads();
    }
    if (t == 255) bsum[blockIdx.x] = sh[255];
    __syncthreads();
    for (int i = t; i < 1024; i += 256) {
        int c = lh[i];
        if (c) atomicAdd(&dhist[i], c);
    }
}

// scan_k2: scan block sums + suffix-scan of dhist (descending-degree bases)
__global__ void scan_k2(const int* __restrict__ bsum, int* __restrict__ boff, int nb,
                        const int* __restrict__ dhist, int* __restrict__ dbase) {
    __shared__ int sh[1024];
    int t = threadIdx.x;
    int v = (t < nb) ? bsum[t] : 0;
    sh[t] = v;
    __syncthreads();
    for (int off = 1; off < 1024; off <<= 1) {
        int u = (t >= off) ? sh[t - off] : 0;
        __syncthreads();
        sh[t] += u;
        __syncthreads();
    }
    if (t < nb) boff[t] = sh[t] - v;
    __syncthreads();
    int rb = 1023 - t;
    int dv = dhist[rb];
    sh[t] = dv;
    __syncthreads();
    for (int off = 1; off < 1024; off <<= 1) {
        int u = (t >= off) ? sh[t - off] : 0;
        __syncthreads();
        sh[t] += u;
        __syncthreads();
    }
    dbase[rb] = sh[t] - dv;
}

// scan_k3 + perm_nodes fused: same grid, both consume deg + precomputed bases.
// Writes row_ptr (exclusive scan) AND nperm (descending-degree counting sort).
__global__ void scan_k3_perm(const int* __restrict__ deg, const int* __restrict__ boff,
                             int* __restrict__ row_ptr, int n,
                             int* __restrict__ dbase, int* __restrict__ nperm) {
    __shared__ int sh[256];
    __shared__ int lh[1024];
    __shared__ int lbase[1024];
    int t = threadIdx.x;
    for (int i = t; i < 1024; i += 256) lh[i] = 0;
    int g = blockIdx.x * 256 + t;
    int v = (g < n) ? deg[g] : 0;
    sh[t] = v;
    __syncthreads();
    for (int off = 1; off < 256; off <<= 1) {
        int u = (t >= off) ? sh[t - off] : 0;
        __syncthreads();
        sh[t] += u;
        __syncthreads();
    }
    if (g < n) {
        int excl = sh[t] - v + boff[blockIdx.x];
        row_ptr[g] = excl;
        if (g == n - 1) row_ptr[n] = excl + v;
    }
    // counting-sort part (lh zeroing was synced by the scan's barriers)
    int b = 0, lrank = 0;
    if (g < n) {
        b = min(v, 1023);
        lrank = atomicAdd(&lh[b], 1);
    }
    __syncthreads();
    for (int i = t; i < 1024; i += 256) {
        int c = lh[i];
        lbase[i] = c ? atomicAdd(&dbase[i], c) : 0;
    }
    __syncthreads();
    if (g < n) nperm[lbase[b] + lrank] = g;
}

// atomic-free permutation: pos = row_ptr[dst] + rank
__global__ void perm_rank_kernel(const int* __restrict__ src, const int* __restrict__ dst,
                                 const int* __restrict__ rank, const int* __restrict__ row_ptr,
                                 int* __restrict__ sorted_src, int E) {
    int i = blockIdx.x * blockDim.x + threadIdx.x;
    int base = i * 8;
    if (base + 8 <= E) {
        int4 d0 = *reinterpret_cast<const int4*>(dst + base);
        int4 d1 = *reinterpret_cast<const int4*>(dst + base + 4);
        int4 s0 = *reinterpret_cast<const int4*>(src + base);
        int4 s1 = *reinterpret_cast<const int4*>(src + base + 4);
        int4 r0 = *reinterpret_cast<const int4*>(rank + base);
        int4 r1 = *reinterpret_cast<const int4*>(rank + base + 4);
        int p0 = row_ptr[d0.x] + r0.x;
        int p1 = row_ptr[d0.y] + r0.y;
        int p2 = row_ptr[d0.z] + r0.z;
        int p3 = row_ptr[d0.w] + r0.w;
        int p4 = row_ptr[d1.x] + r1.x;
        int p5 = row_ptr[d1.y] + r1.y;
        int p6 = row_ptr[d1.z] + r1.z;
        int p7 = row_ptr[d1.w] + r1.w;
        __builtin_nontemporal_store(s0.x, &sorted_src[p0]);
        __builtin_nontemporal_store(s0.y, &sorted_src[p1]);
        __builtin_nontemporal_store(s0.z, &sorted_src[p2]);
        __builtin_nontemporal_store(s0.w, &sorted_src[p3]);
        __builtin_nontemporal_store(s1.x, &sorted_src[p4]);
        __builtin_nontemporal_store(s1.y, &sorted_src[p5]);
        __builtin_nontemporal_store(s1.z, &sorted_src[p6]);
        __builtin_nontemporal_store(s1.w, &sorted_src[p7]);
    } else {
        for (int e = base; e < E; ++e)
            sorted_src[row_ptr[dst[e]] + rank[e]] = src[e];
    }
}

// ---- accumulate 16 bf16 feats (2 x uint4) into fp32 lanes ------------------
__device__ __forceinline__ void acc16(float* ac, uint4 u0, uint4 u1) {
    ac[0]  += __uint_as_float(u0.x << 16);
    ac[1]  += __uint_as_float(u0.x & 0xFFFF0000u);
    ac[2]  += __uint_as_float(u0.y << 16);
    ac[3]  += __uint_as_float(u0.y & 0xFFFF0000u);
    ac[4]  += __uint_as_float(u0.z << 16);
    ac[5]  += __uint_as_float(u0.z & 0xFFFF0000u);
    ac[6]  += __uint_as_float(u0.w << 16);
    ac[7]  += __uint_as_float(u0.w & 0xFFFF0000u);
    ac[8]  += __uint_as_float(u1.x << 16);
    ac[9]  += __uint_as_float(u1.x & 0xFFFF0000u);
    ac[10] += __uint_as_float(u1.y << 16);
    ac[11] += __uint_as_float(u1.y & 0xFFFF0000u);
    ac[12] += __uint_as_float(u1.z << 16);
    ac[13] += __uint_as_float(u1.z & 0xFFFF0000u);
    ac[14] += __uint_as_float(u1.w << 16);
    ac[15] += __uint_as_float(u1.w & 0xFFFF0000u);
}

// ====== fused layer: gather (4-wave split) + LDS reduce + MFMA dense ========
// R4-exact gather (best measured: ILP-2 main + predicated tail).
// Block = 4 waves = one 16-node tile; nperm -> degree-homogeneous tiles.
__global__ void __launch_bounds__(256)
fused_layer(const unsigned short* __restrict__ xb,     // input features (bf16)
            const int* __restrict__ row_ptr,
            const int* __restrict__ sorted_src,
            const int* __restrict__ nperm,
            const unsigned short* __restrict__ Bt,     // [2][64][128] bf16
            const float* __restrict__ bias,
            float* __restrict__ out_f32,
            unsigned short* __restrict__ out_bf16,     // ping-pong output
            int n_nodes, int E, int last) {
    __shared__ float red[4][16][68];    // +4 float pad: <=4-way bank conflicts
    __shared__ int snode[16];           // tile slot -> node id

    int lane = threadIdx.x & 63;
    int w    = threadIdx.x >> 6;        // wave id = edge-subset + out quadrant
    int ln15 = lane & 15;
    int lhi  = lane >> 4;

    int node0 = blockIdx.x << 4;
    int slot  = node0 + ln15;
    int scl   = min(slot, n_nodes - 1);
    int node  = nperm[scl];
    if (lane < 16) snode[lane] = node;  // all waves write same values (benign)

    int beg = row_ptr[node];
    int end = row_ptr[node + 1];
    if (slot >= n_nodes) end = beg;
    int deg = end - beg;

    // tile max degree (reduce over ln15 bits; same result in each lhi group)
    int md = deg;
    md = max(md, __shfl_xor(md, 1));
    md = max(md, __shfl_xor(md, 2));
    md = max(md, __shfl_xor(md, 4));
    md = max(md, __shfl_xor(md, 8));

    float ac[16];
#pragma unroll
    for (int t = 0; t < 16; ++t) ac[t] = 0.f;

    const int Em1 = E - 1;
    int p = w;
    // branchless ILP-2: edges at positions p and p+4 of this node's list
    for (; p + 4 < md; p += 8) {
        int cA = min(beg + p,     Em1);
        int cB = min(beg + p + 4, Em1);
        int sA = sorted_src[cA];
        int sB = sorted_src[cB];
        const unsigned short* rA = xb + (((size_t)(unsigned)sA) << 6) + (lhi << 3);
        const unsigned short* rB = xb + (((size_t)(unsigned)sB) << 6) + (lhi << 3);
        uint4 a0 = *reinterpret_cast<const uint4*>(rA);
        uint4 a1 = *reinterpret_cast<const uint4*>(rA + 32);
        uint4 b0 = *reinterpret_cast<const uint4*>(rB);
        uint4 b1 = *reinterpret_cast<const uint4*>(rB + 32);
        if (p < deg)     acc16(ac, a0, a1);
        if (p + 4 < deg) acc16(ac, b0, b1);
    }
    for (; p < md; p += 4) {
        int cA = min(beg + p, Em1);
        int sA = sorted_src[cA];
        const unsigned short* rA = xb + (((size_t)(unsigned)sA) << 6) + (lhi << 3);
        uint4 a0 = *reinterpret_cast<const uint4*>(rA);
        uint4 a1 = *reinterpret_cast<const uint4*>(rA + 32);
        if (p < deg) acc16(ac, a0, a1);
    }

    // ---- write partials to LDS ----
    int f0 = lhi << 3;
    *reinterpret_cast<float4*>(&red[w][ln15][f0])      = make_float4(ac[0], ac[1], ac[2], ac[3]);
    *reinterpret_cast<float4*>(&red[w][ln15][f0 + 4])  = make_float4(ac[4], ac[5], ac[6], ac[7]);
    *reinterpret_cast<float4*>(&red[w][ln15][32 + f0]) = make_float4(ac[8], ac[9], ac[10], ac[11]);
    *reinterpret_cast<float4*>(&red[w][ln15][36 + f0]) = make_float4(ac[12], ac[13], ac[14], ac[15]);

    // ---- B fragments for this wave's output quadrant (nf = w) ----
    bf16x8 Bf[2][4];
    {
        const unsigned short* bp = Bt + ((size_t)(w * 16 + ln15)) * 128 + (lhi << 3);
#pragma unroll
        for (int pp = 0; pp < 2; ++pp)
#pragma unroll
            for (int kc = 0; kc < 4; ++kc)
                Bf[pp][kc] = *reinterpret_cast<const bf16x8*>(bp + pp * 8192 + kc * 32);
    }
    // self row (A-frags for x)
    const unsigned short* xr = xb + (((size_t)(unsigned)node) << 6) + (lhi << 3);
    bf16x8 A0 = *reinterpret_cast<const bf16x8*>(xr);
    bf16x8 A1 = *reinterpret_cast<const bf16x8*>(xr + 32);
    float bb = bias[w * 16 + ln15];

    __syncthreads();

    // ---- reduce partials across the 4 waves ----
    float s[16];
#pragma unroll
    for (int t = 0; t < 16; ++t) s[t] = 0.f;
#pragma unroll
    for (int ww = 0; ww < 4; ++ww) {
        float4 r0 = *reinterpret_cast<const float4*>(&red[ww][ln15][f0]);
        float4 r1 = *reinterpret_cast<const float4*>(&red[ww][ln15][f0 + 4]);
        float4 r2 = *reinterpret_cast<const float4*>(&red[ww][ln15][32 + f0]);
        float4 r3 = *reinterpret_cast<const float4*>(&red[ww][ln15][36 + f0]);
        s[0]  += r0.x; s[1]  += r0.y; s[2]  += r0.z; s[3]  += r0.w;
        s[4]  += r1.x; s[5]  += r1.y; s[6]  += r1.z; s[7]  += r1.w;
        s[8]  += r2.x; s[9]  += r2.y; s[10] += r2.z; s[11] += r2.w;
        s[12] += r3.x; s[13] += r3.y; s[14] += r3.z; s[15] += r3.w;
    }
    // agg A-frags (bf16 round, same rounding point as unfused version)
    bf16x8 A2, A3;
#pragma unroll
    for (int t = 0; t < 8; ++t) A2[t] = (short)f2bf(s[t]);
#pragma unroll
    for (int t = 0; t < 8; ++t) A3[t] = (short)f2bf(s[8 + t]);

    // ---- MFMA: C quadrant [16 nodes][cols w*16..+15], K=128, hi+lo pass ----
    f32x4 c = {0.f, 0.f, 0.f, 0.f};
    c = __builtin_amdgcn_mfma_f32_16x16x32_bf16(A0, Bf[0][0], c, 0, 0, 0);
    c = __builtin_amdgcn_mfma_f32_16x16x32_bf16(A0, Bf[1][0], c, 0, 0, 0);
    c = __builtin_amdgcn_mfma_f32_16x16x32_bf16(A1, Bf[0][1], c, 0, 0, 0);
    c = __builtin_amdgcn_mfma_f32_16x16x32_bf16(A1, Bf[1][1], c, 0, 0, 0);
    c = __builtin_amdgcn_mfma_f32_16x16x32_bf16(A2, Bf[0][2], c, 0, 0, 0);
    c = __builtin_amdgcn_mfma_f32_16x16x32_bf16(A2, Bf[1][2], c, 0, 0, 0);
    c = __builtin_amdgcn_mfma_f32_16x16x32_bf16(A3, Bf[0][3], c, 0, 0, 0);
    c = __builtin_amdgcn_mfma_f32_16x16x32_bf16(A3, Bf[1][3], c, 0, 0, 0);

    // C/D: col = ln15 (+16*w), tile slot row = node0 + lhi*4 + r -> snode[]
    int colo = w * 16 + ln15;
    if (last) {
#pragma unroll
        for (int r = 0; r < 4; ++r) {
            int sl = lhi * 4 + r;
            if (node0 + sl < n_nodes) {
                int nr = snode[sl];
                out_f32[((size_t)(unsigned)nr << 6) + colo] = c[r] + bb;
            }
        }
    } else {
#pragma unroll
        for (int r = 0; r < 4; ++r) {
            int sl = lhi * 4 + r;
            if (node0 + sl < n_nodes) {
                int nr = snode[sl];
                out_bf16[((size_t)(unsigned)nr << 6) + colo] = f2bf(fmaxf(c[r] + bb, 0.f));
            }
        }
    }
}

// ================= fallback (atomic path, fp32-exact) =======================
__global__ void scatter_kernel(const float* __restrict__ x,
                               const int* __restrict__ src,
                               const int* __restrict__ dst,
                               float* __restrict__ agg, int n_edges) {
    int e = blockIdx.x * (blockDim.x >> 6) + (threadIdx.x >> 6);
    int lane = threadIdx.x & 63;
    if (e >= n_edges) return;
    float v = x[(size_t)src[e] * D + lane];
    unsafeAtomicAdd(&agg[(size_t)dst[e] * D + lane], v);
}

__global__ void dense_kernel(const float* __restrict__ xin,
                             const float* __restrict__ agg,
                             const float* __restrict__ Wself,
                             const float* __restrict__ Wmsg,
                             const float* __restrict__ bias,
                             float* __restrict__ xout,
                             int n_nodes, int do_relu) {
    __shared__ float Ws[D * D];
    __shared__ float Wm[D * D];
    for (int i = threadIdx.x; i < D * D; i += blockDim.x) {
        Ws[i] = Wself[i];
        Wm[i] = Wmsg[i];
    }
    __syncthreads();
    int lane = threadIdx.x & 63;
    int wave = threadIdx.x >> 6;
    int wpb = blockDim.x >> 6;
    float bj = bias[lane];
    for (int n = blockIdx.x * wpb + wave; n < n_nodes; n += gridDim.x * wpb) {
        float xv = xin[(size_t)n * D + lane];
        float av = agg[(size_t)n * D + lane];
        float acc = bj;
#pragma unroll
        for (int k = 0; k < D; ++k) {
            acc += __shfl(xv, k, 64) * Ws[k * D + lane]
                 + __shfl(av, k, 64) * Wm[k * D + lane];
        }
        if (do_relu) acc = fmaxf(acc, 0.f);
        xout[(size_t)n * D + lane] = acc;
    }
}

// ============================================================================
extern "C" void kernel_launch(void* const* d_in, const int* in_sizes, int n_in,
                              void* d_out, int out_size, void* d_ws, size_t ws_size,
                              hipStream_t stream) {
    const float* x0    = (const float*)d_in[0];
    const int*   ei    = (const int*)d_in[1];
    const float* Wmsg  = (const float*)d_in[2];
    const float* Wself = (const float*)d_in[3];
    const float* bias  = (const float*)d_in[4];
    float* out = (float*)d_out;

    const int N = in_sizes[0] / D;         // 50000
    const int E = in_sizes[1] / 2;         // 800000
    const int n_layers = in_sizes[4] / D;  // 3

    const int* src = ei;
    const int* dst = ei + E;
    const size_t NB = (size_t)N * D * sizeof(float);

    const int NBB = (N + 255) / 256;
    const size_t BtB = (size_t)n_layers * 2 * D * 2 * D * 2;  // hi/lo weights, bf16
    const size_t need = (size_t)N * D * 2          // Xb
                      + (size_t)N * D * 2          // Xb2 (ping-pong)
                      + BtB                        // Bt (MFMA weights)
                      + (size_t)E * 4              // sorted_src
                      + (size_t)E * 4              // rank
                      + (size_t)(N + 1) * 4        // row_ptr
                      + (size_t)N * 4              // deg
                      + (size_t)N * 4              // nperm
                      + 1024 * 4 * 2               // dhist + dbase
                      + (size_t)NBB * 4 * 2 + 256; // bsum + boff + slack

    if (ws_size >= need && NBB <= 1024) {
        char* p = (char*)d_ws;
        unsigned short* Xb   = (unsigned short*)p;  p += (size_t)N * D * 2;
        unsigned short* Xb2  = (unsigned short*)p;  p += (size_t)N * D * 2;
        unsigned short* Bt   = (unsigned short*)p;  p += BtB;
        int* sorted_src      = (int*)p;             p += (size_t)E * 4;
        int* rank            = (int*)p;             p += (size_t)E * 4;
        int* row_ptr         = (int*)p;             p += (size_t)(N + 1) * 4;
        int* deg             = (int*)p;             p += (size_t)N * 4;
        int* nperm           = (int*)p;             p += (size_t)N * 4;
        int* dhist           = (int*)p;             p += 1024 * 4;
        int* dbase           = (int*)p;             p += 1024 * 4;
        int* bsum            = (int*)p;             p += (size_t)NBB * 4;
        int* boff            = (int*)p;

        {
            // prep: zero deg/dhist + convert x -> bf16 + build Bt (one dispatch)
            int total = N * D;
            int nthr = (total + 3) / 4;
            prep_kernel<<<(nthr + 255) / 256, 256, 0, stream>>>(
                x0, Xb, total, deg, N, Wself, Wmsg, Bt, n_layers, dhist);

            int threads = 256;
            int nthr8 = (E + 7) / 8;
            int blocks = (nthr8 + threads - 1) / threads;
            hist_rank_kernel<<<blocks, threads, 0, stream>>>(dst, deg, rank, E);
            scan_k1<<<NBB, 256, 0, stream>>>(deg, bsum, N, dhist);
            scan_k2<<<1, 1024, 0, stream>>>(bsum, boff, NBB, dhist, dbase);
            scan_k3_perm<<<NBB, 256, 0, stream>>>(deg, boff, row_ptr, N, dbase, nperm);
            perm_rank_kernel<<<blocks, threads, 0, stream>>>(src, dst, rank, row_ptr,
                                                             sorted_src, E);
        }

        const int dtiles = (N + 15) >> 4;        // 16-node tiles (3125)
        const unsigned short* in_b = Xb;
        unsigned short* out_b = Xb2;

        for (int layer = 0; layer < n_layers; ++layer) {
            fused_layer<<<dtiles, 256, 0, stream>>>(
                in_b, row_ptr, sorted_src, nperm,
                Bt + (size_t)layer * 2 * D * 2 * D,
                bias + (size_t)layer * D,
                out, out_b, N, E, (layer == n_layers - 1) ? 1 : 0);
            // ping-pong
            const unsigned short* t = in_b;
            in_b = out_b;
            out_b = (unsigned short*)t;
        }
    } else {
        // fallback: fp32 atomic path
        float* agg = (float*)d_ws;
        const int EPB = 256 / 64;
        const int scatter_blocks = (E + EPB - 1) / EPB;
        for (int layer = 0; layer < n_layers; ++layer) {
            hipMemsetAsync(agg, 0, NB, stream);
            const float* xin = (layer == 0) ? x0 : out;
            scatter_kernel<<<scatter_blocks, 256, 0, stream>>>(xin, src, dst, agg, E);
            dense_kernel<<<1024, 256, 0, stream>>>(
                xin, agg,
                Wself + (size_t)layer * D * D,
                Wmsg  + (size_t)layer * D * D,
                bias  + (size_t)layer * D,
                out, N, (layer < n_layers - 1) ? 1 : 0);
        }
    }
}